// Round 8
// baseline (236.769 us; speedup 1.0000x reference)
//
#include <hip/hip_runtime.h>
#include <hip/hip_bf16.h>
#include <math.h>

// ---- problem constants (structural, from the reference) ----
#define NB      2
#define QN      12240
#define HW_TOT  12240
#define DIMS    256
#define HEADS   8
#define CH      32
#define LEVELS  4
#define POINTS  4
#define M_TOT   (NB * QN)        // 24480

typedef unsigned short ushort_t;
typedef __attribute__((ext_vector_type(8))) short short8;
typedef __attribute__((ext_vector_type(4))) float floatx4;

__device__ __constant__ int c_Hl[4]    = {96, 48, 24, 12};
__device__ __constant__ int c_Wl[4]    = {96, 48, 24, 12};
__device__ __constant__ int c_start[4] = {0, 9216, 11520, 12096};

__device__ __forceinline__ ushort_t f2bf(float f) {
    __hip_bfloat16 h = __float2bfloat16(f);
    return *reinterpret_cast<ushort_t*>(&h);
}

// =====================================================================
// Fused prep: y=0 -> v,q fp32->bf16 (6120 blocks); y=1 -> weight
// transpose+convert (first 896 blocks: 256 Tin, 384 Tcomb, 256 Tout).
// =====================================================================
__global__ __launch_bounds__(256) void prep_all_kernel(
    const float* __restrict__ v, const float* __restrict__ q,
    const float* __restrict__ W_in, const float* __restrict__ W_off,
    const float* __restrict__ W_attn, const float* __restrict__ W_out,
    const float* __restrict__ b_off, const float* __restrict__ b_attn,
    ushort_t* __restrict__ vbf, ushort_t* __restrict__ qbf,
    ushort_t* __restrict__ Tin, ushort_t* __restrict__ Tcomb,
    ushort_t* __restrict__ Tout, float* __restrict__ bcomb)
{
    const int tid = threadIdx.x;
    if (blockIdx.y == 0) {
        // ---- convert v,q -> bf16, 8 elems/thread ----
        const size_t i = ((size_t)blockIdx.x * 256 + tid) * 8;
        const size_t half = (size_t)M_TOT * DIMS;
        const float* src; ushort_t* dst; size_t off;
        if (i < half) { src = v; dst = vbf; off = i; }
        else          { src = q; dst = qbf; off = i - half; }
        const float4 a = *(const float4*)&src[off];
        const float4 b = *(const float4*)&src[off + 4];
        ushort_t t[8] = {f2bf(a.x), f2bf(a.y), f2bf(a.z), f2bf(a.w),
                         f2bf(b.x), f2bf(b.y), f2bf(b.z), f2bf(b.w)};
        *(int4*)&dst[off] = *(int4*)t;
    } else {
        // ---- weights -> transposed bf16 ----
        const int bx = blockIdx.x;
        if (bx >= 896) return;
        int z, base;
        if      (bx < 256) { z = 0; base = bx; }
        else if (bx < 640) { z = 1; base = bx - 256; }
        else               { z = 2; base = bx - 640; }
        const int gi = base * 256 + tid;
        if (z == 1 && gi < 384)
            bcomb[gi] = (gi < 256) ? b_off[gi] : b_attn[gi - 256];
        const int k = gi & 255;
        const int n = gi >> 8;
        float val; ushort_t* T;
        if (z == 0)      { val = W_in[k * 256 + n];  T = Tin;  }
        else if (z == 1) { val = (n < 256) ? W_off[k * 256 + n]
                                           : W_attn[k * 128 + (n - 256)]; T = Tcomb; }
        else             { val = W_out[k * 256 + n]; T = Tout; }
        T[n * 256 + k] = f2bf(val);
    }
}

// =====================================================================
// Register-B flat GEMM (M >> N, K=256): C[M,Nc] = A[M,K] @ BT[Nc,K]^T.
// Block = 256 thr = 4 waves; wave owns a 32-col strip (2 MFMA tiles);
// its B-frags for ALL of K live in 64 VGPRs (loaded once, no LDS, no
// barriers, no re-load).  Then stream 128 rows as 8 chunks of 16: per
// chunk 8 contiguous 16B A-loads + 16 MFMA (2 indep acc chains).
// #pragma unroll 2 on the chunk loop: pipelining without r6's VGPR
// explosion (232 -> target ~160).  M-tail: clamp loads, guard stores.
// =====================================================================
template<bool C_BF16>
__device__ __forceinline__ void gemm_regb(
    const ushort_t* __restrict__ A, const ushort_t* __restrict__ BT,
    const float* __restrict__ bias, void* __restrict__ Cv,
    int M, int Nc, int bn0, int bm0)
{
    const int tid  = threadIdx.x;
    const int wave = tid >> 6;
    const int lane = tid & 63;
    const int quad = lane >> 4;
    const int l16  = lane & 15;
    const int wn   = bn0 + wave * 32;

    // ---- B fragments for the whole K range: 2 strips x 8 ksteps ----
    short8 breg[2][8];
    #pragma unroll
    for (int s = 0; s < 2; ++s) {
        const ushort_t* bp = BT + (size_t)(wn + s * 16 + l16) * 256 + quad * 8;
        #pragma unroll
        for (int ks = 0; ks < 8; ++ks)
            breg[s][ks] = *(const short8*)(bp + ks * 32);
    }

    const float bias0 = bias[wn + l16];
    const float bias1 = bias[wn + 16 + l16];

    // ---- stream 8 chunks of 16 rows ----
    #pragma unroll 2
    for (int ch = 0; ch < 8; ++ch) {
        int r = bm0 + ch * 16 + l16;
        if (r > M - 1) r = M - 1;
        const ushort_t* ap = A + (size_t)r * 256 + quad * 8;

        short8 a[8];
        #pragma unroll
        for (int ks = 0; ks < 8; ++ks)
            a[ks] = *(const short8*)(ap + ks * 32);

        floatx4 acc0 = {0.f, 0.f, 0.f, 0.f};
        floatx4 acc1 = {0.f, 0.f, 0.f, 0.f};
        #pragma unroll
        for (int ks = 0; ks < 8; ++ks) {
            acc0 = __builtin_amdgcn_mfma_f32_16x16x32_bf16(a[ks], breg[0][ks], acc0, 0, 0, 0);
            acc1 = __builtin_amdgcn_mfma_f32_16x16x32_bf16(a[ks], breg[1][ks], acc1, 0, 0, 0);
        }

        // D row = ch*16 + quad*4 + j, col = strip + l16 (m89 mapping)
        #pragma unroll
        for (int j = 0; j < 4; ++j) {
            const int row = bm0 + ch * 16 + quad * 4 + j;
            if (row >= M) continue;
            const float v0 = acc0[j] + bias0;
            const float v1 = acc1[j] + bias1;
            if (C_BF16) {
                ((ushort_t*)Cv)[(size_t)row * Nc + wn + l16]      = f2bf(v0);
                ((ushort_t*)Cv)[(size_t)row * Nc + wn + 16 + l16] = f2bf(v1);
            } else {
                ((float*)Cv)[(size_t)row * Nc + wn + l16]      = v0;
                ((float*)Cv)[(size_t)row * Nc + wn + 16 + l16] = v1;
            }
        }
    }
}

// Fused projection GEMMs: y<2 -> vproj = v@W_in (bf16 out, Nc=256);
// y in 2..4 -> offlog = q@[W_off|W_attn] (fp32 out, Nc=384).
__global__ __launch_bounds__(256) void gemm_proj_kernel(
    const ushort_t* __restrict__ vbf, const ushort_t* __restrict__ qbf,
    const ushort_t* __restrict__ Tin, const ushort_t* __restrict__ Tcomb,
    const float* __restrict__ b_in, const float* __restrict__ bcomb,
    ushort_t* __restrict__ vproj, float* __restrict__ offlog)
{
    const int bm0 = blockIdx.x * 128;
    const int y = blockIdx.y;
    if (y < 2)
        gemm_regb<true>(vbf, Tin, b_in, vproj, M_TOT, 256, y * 128, bm0);
    else
        gemm_regb<false>(qbf, Tcomb, bcomb, offlog, M_TOT, 384, (y - 2) * 128, bm0);
}

__global__ __launch_bounds__(256) void gemm_out_kernel(
    const ushort_t* __restrict__ mid, const ushort_t* __restrict__ Tout,
    const float* __restrict__ b_out, float* __restrict__ out)
{
    gemm_regb<false>(mid, Tout, b_out, out, M_TOT, 256,
                     blockIdx.y * 128, blockIdx.x * 128);
}

// =====================================================================
// Sampling kernel v5 (known 72 us): 2 queries per 128-thread block,
// 8B bf16 gathers.  L3-BW-bound (~800 MB gather traffic) -- near its
// structural floor; left untouched.
// =====================================================================
#define QB 2
#define SLOTS 576

__global__ __launch_bounds__(128) void msda_sample_kernel(
    const ushort_t* __restrict__ vproj, const float* __restrict__ offlog,
    const float* __restrict__ p, ushort_t* __restrict__ mid)
{
    __shared__ float s_logit[QB][128];
    __shared__ float s_off[QB][256];
    __shared__ float s_p[QB][8];
    __shared__ float s_mx[QB][HEADS];
    __shared__ float s_inv[QB][HEADS];
    __shared__ float s_w[QB][SLOTS];
    __shared__ int   s_idx[QB][SLOTS];

    const int tid = threadIdx.x;          // 0..127
    const int bq0 = blockIdx.x * QB;

    #pragma unroll
    for (int i = tid; i < QB * 256; i += 128) {
        int sub = i >> 8, j = i & 255;
        s_off[sub][j] = offlog[(size_t)(bq0 + sub) * 384 + j];
    }
    #pragma unroll
    for (int i = tid; i < QB * 128; i += 128) {
        int sub = i >> 7, j = i & 127;
        s_logit[sub][j] = offlog[(size_t)(bq0 + sub) * 384 + 256 + j];
    }
    if (tid < QB * 8) {
        int sub = tid >> 3, j = tid & 7;
        s_p[sub][j] = p[(size_t)(bq0 + sub) * 8 + j];
    }
    __syncthreads();

    if (tid < QB * HEADS) {
        int sub = tid >> 3, h = tid & 7;
        float mx = -1e30f;
        #pragma unroll
        for (int i = 0; i < 16; ++i) mx = fmaxf(mx, s_logit[sub][h * 16 + i]);
        float ssum = 0.0f;
        #pragma unroll
        for (int i = 0; i < 16; ++i) ssum += __expf(s_logit[sub][h * 16 + i] - mx);
        s_mx[sub][h] = mx;
        s_inv[sub][h] = 1.0f / ssum;
    }
    __syncthreads();

    // ---- phase 1: 256 tasks (sub, h, l, pt) over 128 threads ----
    #pragma unroll
    for (int tt = tid; tt < QB * 128; tt += 128) {
        const int sub = tt >> 7;
        const int j   = tt & 127;          // h*16 + l*4 + pt
        const int h   = j >> 4;
        const int l   = (j >> 2) & 3;
        const int nq  = bq0 + sub;
        const int nb  = (nq >= QN) ? 1 : 0;

        const int Hl = c_Hl[l], Wl = c_Wl[l], st = c_start[l];
        const float fW = (float)Wl, fH = (float)Hl;

        const float w = __expf(s_logit[sub][j] - s_mx[sub][h]) * s_inv[sub][h];

        const int oi = j * 2;
        const float ox = s_off[sub][oi];
        const float oy = s_off[sub][oi + 1];
        const float px = s_p[sub][l * 2 + 0];
        const float py = s_p[sub][l * 2 + 1];

        const float lx = px + ox / fW;
        const float ly = py + oy / fH;
        const float x = lx * fW - 0.5f;
        const float y = ly * fH - 0.5f;

        const float x0f = floorf(x), y0f = floorf(y);
        const int x0 = (int)x0f, y0 = (int)y0f;
        const float dx = x - x0f, dy = y - y0f;

        const int base = nb * (HW_TOT * DIMS) + h * CH;
        const int slot = (j & 15) * 36 + h * 4;

        const bool vx0 = (x0 >= 0) & (x0 < Wl);
        const bool vx1 = (x0 + 1 >= 0) & (x0 + 1 < Wl);
        const bool vy0 = (y0 >= 0) & (y0 < Hl);
        const bool vy1 = (y0 + 1 >= 0) & (y0 + 1 < Hl);

        s_w[sub][slot + 0] = (vx0 & vy0) ? w * (1.0f - dx) * (1.0f - dy) : 0.0f;
        s_w[sub][slot + 1] = (vx1 & vy0) ? w * dx * (1.0f - dy) : 0.0f;
        s_w[sub][slot + 2] = (vx0 & vy1) ? w * (1.0f - dx) * dy : 0.0f;
        s_w[sub][slot + 3] = (vx1 & vy1) ? w * dx * dy : 0.0f;
        s_idx[sub][slot + 0] = (vx0 & vy0) ? base + (st + y0 * Wl + x0) * DIMS : 0;
        s_idx[sub][slot + 1] = (vx1 & vy0) ? base + (st + y0 * Wl + x0 + 1) * DIMS : 0;
        s_idx[sub][slot + 2] = (vx0 & vy1) ? base + (st + (y0 + 1) * Wl + x0) * DIMS : 0;
        s_idx[sub][slot + 3] = (vx1 & vy1) ? base + (st + (y0 + 1) * Wl + x0 + 1) * DIMS : 0;
    }
    __syncthreads();

    // ---- phase 2: bf16 gathers (uint2 = 4 channels), fp32 accumulate ----
    const int sub  = tid >> 6;
    const int lane = tid & 63;
    const int h    = lane >> 3;
    const int c4   = lane & 7;
    const int nq   = bq0 + sub;

    float ax = 0.0f, ay = 0.0f, az = 0.0f, aw = 0.0f;
    const ushort_t* __restrict__ vb = vproj + c4 * 4;

    #pragma unroll
    for (int t = 0; t < 16; ++t) {
        const int slot = t * 36 + h * 4;
        const int4   I = *(const int4*)&s_idx[sub][slot];
        const float4 W = *(const float4*)&s_w[sub][slot];

        const uint2 g0 = *(const uint2*)(vb + I.x);
        const uint2 g1 = *(const uint2*)(vb + I.y);
        const uint2 g2 = *(const uint2*)(vb + I.z);
        const uint2 g3 = *(const uint2*)(vb + I.w);

        ax = fmaf(W.x, __uint_as_float(g0.x << 16), ax);
        ay = fmaf(W.x, __uint_as_float(g0.x & 0xffff0000u), ay);
        az = fmaf(W.x, __uint_as_float(g0.y << 16), az);
        aw = fmaf(W.x, __uint_as_float(g0.y & 0xffff0000u), aw);

        ax = fmaf(W.y, __uint_as_float(g1.x << 16), ax);
        ay = fmaf(W.y, __uint_as_float(g1.x & 0xffff0000u), ay);
        az = fmaf(W.y, __uint_as_float(g1.y << 16), az);
        aw = fmaf(W.y, __uint_as_float(g1.y & 0xffff0000u), aw);

        ax = fmaf(W.z, __uint_as_float(g2.x << 16), ax);
        ay = fmaf(W.z, __uint_as_float(g2.x & 0xffff0000u), ay);
        az = fmaf(W.z, __uint_as_float(g2.y << 16), az);
        aw = fmaf(W.z, __uint_as_float(g2.y & 0xffff0000u), aw);

        ax = fmaf(W.w, __uint_as_float(g3.x << 16), ax);
        ay = fmaf(W.w, __uint_as_float(g3.x & 0xffff0000u), ay);
        az = fmaf(W.w, __uint_as_float(g3.y << 16), az);
        aw = fmaf(W.w, __uint_as_float(g3.y & 0xffff0000u), aw);
    }

    ushort_t mv[4] = {f2bf(ax), f2bf(ay), f2bf(az), f2bf(aw)};
    *(uint2*)&mid[(size_t)nq * DIMS + lane * 4] = *(uint2*)mv;
}

// =====================================================================
extern "C" void kernel_launch(void* const* d_in, const int* in_sizes, int n_in,
                              void* d_out, int out_size, void* d_ws, size_t ws_size,
                              hipStream_t stream)
{
    const float* q      = (const float*)d_in[0];
    const float* p      = (const float*)d_in[1];
    const float* v      = (const float*)d_in[2];
    const float* W_off  = (const float*)d_in[3];
    const float* b_off  = (const float*)d_in[4];
    const float* W_attn = (const float*)d_in[5];
    const float* b_attn = (const float*)d_in[6];
    const float* W_in   = (const float*)d_in[7];
    const float* b_in   = (const float*)d_in[8];
    const float* W_out  = (const float*)d_in[9];
    const float* b_out  = (const float*)d_in[10];
    float* out = (float*)d_out;

    const int M = M_TOT;                            // 24480

    // workspace layout (mid aliases vbf -- vbf dead after proj GEMM)
    ushort_t* vproj  = (ushort_t*)d_ws;                          // M*256 bf16
    float*    offlog = (float*)(vproj + (size_t)M * 256);        // M*384 f32
    ushort_t* vbf    = (ushort_t*)(offlog + (size_t)M * 384);    // M*256 bf16
    ushort_t* mid    = vbf;                                      // alias
    ushort_t* qbf    = vbf + (size_t)M * 256;                    // M*256 bf16
    ushort_t* Tin    = qbf + (size_t)M * 256;
    ushort_t* Tcomb  = Tin + 256 * 256;
    ushort_t* Tout   = Tcomb + 384 * 256;
    float*    bcomb  = (float*)(Tout + 256 * 256);

    // 0) fused: v,q -> bf16 (y=0) + weight transpose/convert (y=1)
    prep_all_kernel<<<dim3(6120, 2), 256, 0, stream>>>(
        v, q, W_in, W_off, W_attn, W_out, b_off, b_attn,
        vbf, qbf, Tin, Tcomb, Tout, bcomb);

    // 1+2+3) fused projection GEMMs (register-B flat GEMM)
    gemm_proj_kernel<<<dim3(192, 5), 256, 0, stream>>>(
        vbf, qbf, Tin, Tcomb, b_in, bcomb, vproj, offlog);
    // 4) softmax + bilinear sampling -> bf16 mid
    msda_sample_kernel<<<dim3(M / QB), 128, 0, stream>>>(vproj, offlog, p, mid);
    // 5) out = mid @ W_out + b_out
    gemm_out_kernel<<<dim3(192, 2), 256, 0, stream>>>(mid, Tout, b_out, out);
}

// Round 9
// 211.260 us; speedup vs baseline: 1.1207x; 1.1207x over previous
//
#include <hip/hip_runtime.h>
#include <hip/hip_bf16.h>
#include <math.h>

// ---- problem constants (structural, from the reference) ----
#define NB      2
#define QN      12240
#define HW_TOT  12240
#define DIMS    256
#define HEADS   8
#define CH      32
#define LEVELS  4
#define POINTS  4
#define M_TOT   (NB * QN)        // 24480

typedef unsigned short ushort_t;
typedef __attribute__((ext_vector_type(8))) short short8;
typedef __attribute__((ext_vector_type(4))) float floatx4;

__device__ __constant__ int c_Hl[4]    = {96, 48, 24, 12};
__device__ __constant__ int c_Wl[4]    = {96, 48, 24, 12};
__device__ __constant__ int c_start[4] = {0, 9216, 11520, 12096};

__device__ __forceinline__ ushort_t f2bf(float f) {
    __hip_bfloat16 h = __float2bfloat16(f);
    return *reinterpret_cast<ushort_t*>(&h);
}

// =====================================================================
// Weights -> transposed bf16 (WT[n][k]); z=1 also builds the fused
// off+attn weight [384][256] and its combined bias.
// =====================================================================
__global__ __launch_bounds__(256) void prep_weights_kernel(
    const float* __restrict__ W_in, const float* __restrict__ W_off,
    const float* __restrict__ W_attn, const float* __restrict__ W_out,
    const float* __restrict__ b_off, const float* __restrict__ b_attn,
    ushort_t* __restrict__ Tin, ushort_t* __restrict__ Tcomb,
    ushort_t* __restrict__ Tout, float* __restrict__ bcomb)
{
    const int z  = blockIdx.z;
    const int gi = blockIdx.x * 256 + threadIdx.x;
    if (z == 1 && gi < 384)
        bcomb[gi] = (gi < 256) ? b_off[gi] : b_attn[gi - 256];
    const int Nw = (z == 1) ? 384 : 256;
    if (gi >= Nw * 256) return;
    const int k = gi & 255;       // coalesced write along k
    const int n = gi >> 8;
    float val; ushort_t* T;
    if (z == 0)      { val = W_in[k * 256 + n];  T = Tin;  }
    else if (z == 1) { val = (n < 256) ? W_off[k * 256 + n]
                                       : W_attn[k * 128 + (n - 256)]; T = Tcomb; }
    else             { val = W_out[k * 256 + n]; T = Tout; }
    T[n * 256 + k] = f2bf(val);
}

// =====================================================================
// m97-style bf16 MFMA GEMM core (the 208.6-us config's GEMM), extended:
// AF32=true -> A is fp32, converted to bf16 in VGPRs during staging
// (ds_write; kills the standalone convert pass).  AF32=false -> A is
// bf16, staged via global_load_lds width=16 (wave-uniform base, m104).
// B always bf16 via global_load_lds.  128x128 tile, BK=32, 4 waves 2x2,
// wave = 64x64 via 4x4 v_mfma_f32_16x16x32_bf16.
// M-tail: load rows clamped to M-1, stores guarded.
// =====================================================================
template<bool AF32, bool C_BF16>
__device__ __forceinline__ void gemm_core(
    const void* __restrict__ Aptr, const ushort_t* __restrict__ BT,
    const float* __restrict__ bias, void* __restrict__ Cv,
    int M, int Nc, int bm0, int bn0,
    ushort_t* __restrict__ As, ushort_t* __restrict__ Bs)
{
    const int tid  = threadIdx.x;
    const int wave = tid >> 6;
    const int lane = tid & 63;
    const int quad = lane >> 4;
    const int l16  = lane & 15;
    const int wm   = (wave >> 1) * 64;
    const int wn   = (wave & 1) * 64;

    // ---- B staging geometry (global_load_lds): byte off = tid*16 ----
    const int off0 = tid * 16;
    const int brow = off0 >> 6;           // 0..63 (64B = 32 bf16 per row)
    const int bkc  = (off0 & 63) >> 1;    // element k-offset: 0/8/16/24
    const ushort_t* gb0 = BT + (size_t)(bn0 + brow) * 256 + bkc;
    const ushort_t* gb1 = BT + (size_t)(bn0 + brow + 64) * 256 + bkc;
    ushort_t* lB0 = Bs + wave * 512;          // wave-uniform bases
    ushort_t* lB1 = Bs + wave * 512 + 2048;

    // ---- A staging geometry ----
    // AF32: thread converts 16 fp32 -> 16 bf16 per iter (ds_write).
    const int arow32 = tid >> 1;              // 0..127
    const int akc32  = (tid & 1) * 16;        // 0 or 16
    int arA = bm0 + arow32; if (arA > M - 1) arA = M - 1;
    const float* apf = (const float*)Aptr + (size_t)arA * 256 + akc32;
    // !AF32: same DMA pattern as B.
    int ar0 = bm0 + brow;      if (ar0 > M - 1) ar0 = M - 1;
    int ar1 = bm0 + brow + 64; if (ar1 > M - 1) ar1 = M - 1;
    const ushort_t* ga0 = (const ushort_t*)Aptr + (size_t)ar0 * 256 + bkc;
    const ushort_t* ga1 = (const ushort_t*)Aptr + (size_t)ar1 * 256 + bkc;
    ushort_t* lA0 = As + wave * 512;
    ushort_t* lA1 = As + wave * 512 + 2048;

    floatx4 acc[4][4];
    #pragma unroll
    for (int i = 0; i < 4; ++i)
        #pragma unroll
        for (int j = 0; j < 4; ++j)
            acc[i][j] = (floatx4){0.f, 0.f, 0.f, 0.f};

    for (int kk = 0; kk < 256; kk += 32) {
        if (AF32) {
            const float4 f0 = *(const float4*)(apf + kk);
            const float4 f1 = *(const float4*)(apf + kk + 4);
            const float4 f2 = *(const float4*)(apf + kk + 8);
            const float4 f3 = *(const float4*)(apf + kk + 12);
            ushort_t t[16] = {f2bf(f0.x), f2bf(f0.y), f2bf(f0.z), f2bf(f0.w),
                              f2bf(f1.x), f2bf(f1.y), f2bf(f1.z), f2bf(f1.w),
                              f2bf(f2.x), f2bf(f2.y), f2bf(f2.z), f2bf(f2.w),
                              f2bf(f3.x), f2bf(f3.y), f2bf(f3.z), f2bf(f3.w)};
            *(int4*)&As[arow32 * 32 + akc32]     = *(int4*)&t[0];
            *(int4*)&As[arow32 * 32 + akc32 + 8] = *(int4*)&t[8];
        } else {
            __builtin_amdgcn_global_load_lds(
                (const __attribute__((address_space(1))) void*)(ga0 + kk),
                (__attribute__((address_space(3))) void*)lA0, 16, 0, 0);
            __builtin_amdgcn_global_load_lds(
                (const __attribute__((address_space(1))) void*)(ga1 + kk),
                (__attribute__((address_space(3))) void*)lA1, 16, 0, 0);
        }
        __builtin_amdgcn_global_load_lds(
            (const __attribute__((address_space(1))) void*)(gb0 + kk),
            (__attribute__((address_space(3))) void*)lB0, 16, 0, 0);
        __builtin_amdgcn_global_load_lds(
            (const __attribute__((address_space(1))) void*)(gb1 + kk),
            (__attribute__((address_space(3))) void*)lB1, 16, 0, 0);
        __syncthreads();

        short8 af[4], bfr[4];
        #pragma unroll
        for (int mt = 0; mt < 4; ++mt)
            af[mt] = *(const short8*)&As[(wm + mt * 16 + l16) * 32 + quad * 8];
        #pragma unroll
        for (int nt = 0; nt < 4; ++nt)
            bfr[nt] = *(const short8*)&Bs[(wn + nt * 16 + l16) * 32 + quad * 8];
        #pragma unroll
        for (int mt = 0; mt < 4; ++mt)
            #pragma unroll
            for (int nt = 0; nt < 4; ++nt)
                acc[mt][nt] = __builtin_amdgcn_mfma_f32_16x16x32_bf16(
                    af[mt], bfr[nt], acc[mt][nt], 0, 0, 0);
        __syncthreads();
    }

    // epilogue: D row = wm+mt*16+quad*4+j, col = wn+nt*16+l16 (m89 mapping)
    #pragma unroll
    for (int mt = 0; mt < 4; ++mt) {
        #pragma unroll
        for (int j = 0; j < 4; ++j) {
            const int row = bm0 + wm + mt * 16 + quad * 4 + j;
            if (row >= M) continue;
            #pragma unroll
            for (int nt = 0; nt < 4; ++nt) {
                const int col = bn0 + wn + nt * 16 + l16;
                const float val = acc[mt][nt][j] + bias[col];
                if (C_BF16) ((ushort_t*)Cv)[(size_t)row * Nc + col] = f2bf(val);
                else        ((float*)Cv)[(size_t)row * Nc + col]    = val;
            }
        }
    }
}

// Fused projection GEMMs (fp32 A, conversion in staging):
// y<2 -> vproj = v@W_in (bf16 out, Nc=256);
// y in 2..4 -> offlog = q@[W_off|W_attn] (fp32 out, Nc=384).
__global__ __launch_bounds__(256) void gemm_proj_kernel(
    const float* __restrict__ v, const float* __restrict__ q,
    const ushort_t* __restrict__ Tin, const ushort_t* __restrict__ Tcomb,
    const float* __restrict__ b_in, const float* __restrict__ bcomb,
    ushort_t* __restrict__ vproj, float* __restrict__ offlog)
{
    __shared__ ushort_t As[128 * 32];
    __shared__ ushort_t Bs[128 * 32];
    const int bm0 = blockIdx.x * 128;
    const int y = blockIdx.y;
    if (y < 2)
        gemm_core<true, true>(v, Tin, b_in, vproj, M_TOT, 256, bm0, y * 128, As, Bs);
    else
        gemm_core<true, false>(q, Tcomb, bcomb, offlog, M_TOT, 384, bm0, (y - 2) * 128, As, Bs);
}

__global__ __launch_bounds__(256) void gemm_out_kernel(
    const ushort_t* __restrict__ mid, const ushort_t* __restrict__ Tout,
    const float* __restrict__ b_out, float* __restrict__ out)
{
    __shared__ ushort_t As[128 * 32];
    __shared__ ushort_t Bs[128 * 32];
    gemm_core<false, false>(mid, Tout, b_out, out, M_TOT, 256,
                            blockIdx.x * 128, blockIdx.y * 128, As, Bs);
}

// =====================================================================
// Sampling kernel v5 (measured 70-73 us): 2 queries per 128-thread
// block, 8B bf16 gathers, slot stride 36 floats.
// =====================================================================
#define QB 2
#define SLOTS 576

__global__ __launch_bounds__(128) void msda_sample_kernel(
    const ushort_t* __restrict__ vproj, const float* __restrict__ offlog,
    const float* __restrict__ p, ushort_t* __restrict__ mid)
{
    __shared__ float s_logit[QB][128];
    __shared__ float s_off[QB][256];
    __shared__ float s_p[QB][8];
    __shared__ float s_mx[QB][HEADS];
    __shared__ float s_inv[QB][HEADS];
    __shared__ float s_w[QB][SLOTS];
    __shared__ int   s_idx[QB][SLOTS];

    const int tid = threadIdx.x;          // 0..127
    const int bq0 = blockIdx.x * QB;

    #pragma unroll
    for (int i = tid; i < QB * 256; i += 128) {
        int sub = i >> 8, j = i & 255;
        s_off[sub][j] = offlog[(size_t)(bq0 + sub) * 384 + j];
    }
    #pragma unroll
    for (int i = tid; i < QB * 128; i += 128) {
        int sub = i >> 7, j = i & 127;
        s_logit[sub][j] = offlog[(size_t)(bq0 + sub) * 384 + 256 + j];
    }
    if (tid < QB * 8) {
        int sub = tid >> 3, j = tid & 7;
        s_p[sub][j] = p[(size_t)(bq0 + sub) * 8 + j];
    }
    __syncthreads();

    if (tid < QB * HEADS) {
        int sub = tid >> 3, h = tid & 7;
        float mx = -1e30f;
        #pragma unroll
        for (int i = 0; i < 16; ++i) mx = fmaxf(mx, s_logit[sub][h * 16 + i]);
        float ssum = 0.0f;
        #pragma unroll
        for (int i = 0; i < 16; ++i) ssum += __expf(s_logit[sub][h * 16 + i] - mx);
        s_mx[sub][h] = mx;
        s_inv[sub][h] = 1.0f / ssum;
    }
    __syncthreads();

    // ---- phase 1: 256 tasks (sub, h, l, pt) over 128 threads ----
    #pragma unroll
    for (int tt = tid; tt < QB * 128; tt += 128) {
        const int sub = tt >> 7;
        const int j   = tt & 127;          // h*16 + l*4 + pt
        const int h   = j >> 4;
        const int l   = (j >> 2) & 3;
        const int nq  = bq0 + sub;
        const int nb  = (nq >= QN) ? 1 : 0;

        const int Hl = c_Hl[l], Wl = c_Wl[l], st = c_start[l];
        const float fW = (float)Wl, fH = (float)Hl;

        const float w = __expf(s_logit[sub][j] - s_mx[sub][h]) * s_inv[sub][h];

        const int oi = j * 2;
        const float ox = s_off[sub][oi];
        const float oy = s_off[sub][oi + 1];
        const float px = s_p[sub][l * 2 + 0];
        const float py = s_p[sub][l * 2 + 1];

        const float lx = px + ox / fW;
        const float ly = py + oy / fH;
        const float x = lx * fW - 0.5f;
        const float y = ly * fH - 0.5f;

        const float x0f = floorf(x), y0f = floorf(y);
        const int x0 = (int)x0f, y0 = (int)y0f;
        const float dx = x - x0f, dy = y - y0f;

        const int base = nb * (HW_TOT * DIMS) + h * CH;
        const int slot = (j & 15) * 36 + h * 4;

        const bool vx0 = (x0 >= 0) & (x0 < Wl);
        const bool vx1 = (x0 + 1 >= 0) & (x0 + 1 < Wl);
        const bool vy0 = (y0 >= 0) & (y0 < Hl);
        const bool vy1 = (y0 + 1 >= 0) & (y0 + 1 < Hl);

        s_w[sub][slot + 0] = (vx0 & vy0) ? w * (1.0f - dx) * (1.0f - dy) : 0.0f;
        s_w[sub][slot + 1] = (vx1 & vy0) ? w * dx * (1.0f - dy) : 0.0f;
        s_w[sub][slot + 2] = (vx0 & vy1) ? w * (1.0f - dx) * dy : 0.0f;
        s_w[sub][slot + 3] = (vx1 & vy1) ? w * dx * dy : 0.0f;
        s_idx[sub][slot + 0] = (vx0 & vy0) ? base + (st + y0 * Wl + x0) * DIMS : 0;
        s_idx[sub][slot + 1] = (vx1 & vy0) ? base + (st + y0 * Wl + x0 + 1) * DIMS : 0;
        s_idx[sub][slot + 2] = (vx0 & vy1) ? base + (st + (y0 + 1) * Wl + x0) * DIMS : 0;
        s_idx[sub][slot + 3] = (vx1 & vy1) ? base + (st + (y0 + 1) * Wl + x0 + 1) * DIMS : 0;
    }
    __syncthreads();

    // ---- phase 2: bf16 gathers (uint2 = 4 channels), fp32 accumulate ----
    const int sub  = tid >> 6;
    const int lane = tid & 63;
    const int h    = lane >> 3;
    const int c4   = lane & 7;
    const int nq   = bq0 + sub;

    float ax = 0.0f, ay = 0.0f, az = 0.0f, aw = 0.0f;
    const ushort_t* __restrict__ vb = vproj + c4 * 4;

    #pragma unroll
    for (int t = 0; t < 16; ++t) {
        const int slot = t * 36 + h * 4;
        const int4   I = *(const int4*)&s_idx[sub][slot];
        const float4 W = *(const float4*)&s_w[sub][slot];

        const uint2 g0 = *(const uint2*)(vb + I.x);
        const uint2 g1 = *(const uint2*)(vb + I.y);
        const uint2 g2 = *(const uint2*)(vb + I.z);
        const uint2 g3 = *(const uint2*)(vb + I.w);

        ax = fmaf(W.x, __uint_as_float(g0.x << 16), ax);
        ay = fmaf(W.x, __uint_as_float(g0.x & 0xffff0000u), ay);
        az = fmaf(W.x, __uint_as_float(g0.y << 16), az);
        aw = fmaf(W.x, __uint_as_float(g0.y & 0xffff0000u), aw);

        ax = fmaf(W.y, __uint_as_float(g1.x << 16), ax);
        ay = fmaf(W.y, __uint_as_float(g1.x & 0xffff0000u), ay);
        az = fmaf(W.y, __uint_as_float(g1.y << 16), az);
        aw = fmaf(W.y, __uint_as_float(g1.y & 0xffff0000u), aw);

        ax = fmaf(W.z, __uint_as_float(g2.x << 16), ax);
        ay = fmaf(W.z, __uint_as_float(g2.x & 0xffff0000u), ay);
        az = fmaf(W.z, __uint_as_float(g2.y << 16), az);
        aw = fmaf(W.z, __uint_as_float(g2.y & 0xffff0000u), aw);

        ax = fmaf(W.w, __uint_as_float(g3.x << 16), ax);
        ay = fmaf(W.w, __uint_as_float(g3.x & 0xffff0000u), ay);
        az = fmaf(W.w, __uint_as_float(g3.y << 16), az);
        aw = fmaf(W.w, __uint_as_float(g3.y & 0xffff0000u), aw);
    }

    ushort_t mv[4] = {f2bf(ax), f2bf(ay), f2bf(az), f2bf(aw)};
    *(uint2*)&mid[(size_t)nq * DIMS + lane * 4] = *(uint2*)mv;
}

// =====================================================================
extern "C" void kernel_launch(void* const* d_in, const int* in_sizes, int n_in,
                              void* d_out, int out_size, void* d_ws, size_t ws_size,
                              hipStream_t stream)
{
    const float* q      = (const float*)d_in[0];
    const float* p      = (const float*)d_in[1];
    const float* v      = (const float*)d_in[2];
    const float* W_off  = (const float*)d_in[3];
    const float* b_off  = (const float*)d_in[4];
    const float* W_attn = (const float*)d_in[5];
    const float* b_attn = (const float*)d_in[6];
    const float* W_in   = (const float*)d_in[7];
    const float* b_in   = (const float*)d_in[8];
    const float* W_out  = (const float*)d_in[9];
    const float* b_out  = (const float*)d_in[10];
    float* out = (float*)d_out;

    const int M = M_TOT;                            // 24480

    // workspace layout
    ushort_t* vproj  = (ushort_t*)d_ws;                          // M*256 bf16
    float*    offlog = (float*)(vproj + (size_t)M * 256);        // M*384 f32
    ushort_t* mid    = (ushort_t*)(offlog + (size_t)M * 384);    // M*256 bf16
    ushort_t* Tin    = mid + (size_t)M * 256;
    ushort_t* Tcomb  = Tin + 256 * 256;
    ushort_t* Tout   = Tcomb + 384 * 256;
    float*    bcomb  = (float*)(Tout + 256 * 256);

    // 0) weights -> transposed bf16 (+ fused off/attn weight & bias)
    prep_weights_kernel<<<dim3(384, 1, 3), 256, 0, stream>>>(
        W_in, W_off, W_attn, W_out, b_off, b_attn, Tin, Tcomb, Tout, bcomb);

    // 1+2+3) fused projection GEMMs (fp32 A, convert-in-staging)
    gemm_proj_kernel<<<dim3(192, 5), 256, 0, stream>>>(
        v, q, Tin, Tcomb, b_in, bcomb, vproj, offlog);
    // 4) softmax + bilinear sampling -> bf16 mid
    msda_sample_kernel<<<dim3(M / QB), 128, 0, stream>>>(vproj, offlog, p, mid);
    // 5) out = mid @ W_out + b_out
    gemm_out_kernel<<<dim3(192, 2), 256, 0, stream>>>(mid, Tout, b_out, out);
}

// Round 10
// 210.015 us; speedup vs baseline: 1.1274x; 1.0059x over previous
//
#include <hip/hip_runtime.h>
#include <hip/hip_bf16.h>
#include <math.h>

// ---- problem constants (structural, from the reference) ----
#define NB      2
#define QN      12240
#define HW_TOT  12240
#define DIMS    256
#define HEADS   8
#define CH      32
#define LEVELS  4
#define POINTS  4
#define M_TOT   (NB * QN)        // 24480

typedef unsigned short ushort_t;
typedef __attribute__((ext_vector_type(8))) short short8;
typedef __attribute__((ext_vector_type(4))) float floatx4;

__device__ __constant__ int c_Hl[4]    = {96, 48, 24, 12};
__device__ __constant__ int c_Wl[4]    = {96, 48, 24, 12};
__device__ __constant__ int c_start[4] = {0, 9216, 11520, 12096};

__device__ __forceinline__ ushort_t f2bf(float f) {
    __hip_bfloat16 h = __float2bfloat16(f);
    return *reinterpret_cast<ushort_t*>(&h);
}

// =====================================================================
// Elementwise fp32 -> bf16 for v and q (one pass, 8 elems/thread).
// =====================================================================
__global__ __launch_bounds__(256) void convert_qv_kernel(
    const float* __restrict__ v, const float* __restrict__ q,
    ushort_t* __restrict__ vbf, ushort_t* __restrict__ qbf)
{
    const size_t i = ((size_t)blockIdx.x * 256 + threadIdx.x) * 8;
    const size_t half = (size_t)M_TOT * DIMS;
    const float* src; ushort_t* dst; size_t off;
    if (i < half) { src = v; dst = vbf; off = i; }
    else          { src = q; dst = qbf; off = i - half; }
    const float4 a = *(const float4*)&src[off];
    const float4 b = *(const float4*)&src[off + 4];
    ushort_t t[8] = {f2bf(a.x), f2bf(a.y), f2bf(a.z), f2bf(a.w),
                     f2bf(b.x), f2bf(b.y), f2bf(b.z), f2bf(b.w)};
    *(int4*)&dst[off] = *(int4*)t;
}

// =====================================================================
// Weights -> transposed bf16 (WT[n][k]); z=1 also builds the fused
// off+attn weight [384][256] and its combined bias.
// =====================================================================
__global__ __launch_bounds__(256) void prep_weights_kernel(
    const float* __restrict__ W_in, const float* __restrict__ W_off,
    const float* __restrict__ W_attn, const float* __restrict__ W_out,
    const float* __restrict__ b_off, const float* __restrict__ b_attn,
    ushort_t* __restrict__ Tin, ushort_t* __restrict__ Tcomb,
    ushort_t* __restrict__ Tout, float* __restrict__ bcomb)
{
    const int z  = blockIdx.z;
    const int gi = blockIdx.x * 256 + threadIdx.x;
    if (z == 1 && gi < 384)
        bcomb[gi] = (gi < 256) ? b_off[gi] : b_attn[gi - 256];
    const int Nw = (z == 1) ? 384 : 256;
    if (gi >= Nw * 256) return;
    const int k = gi & 255;       // coalesced write along k
    const int n = gi >> 8;
    float val; ushort_t* T;
    if (z == 0)      { val = W_in[k * 256 + n];  T = Tin;  }
    else if (z == 1) { val = (n < 256) ? W_off[k * 256 + n]
                                       : W_attn[k * 128 + (n - 256)]; T = Tcomb; }
    else             { val = W_out[k * 256 + n]; T = Tout; }
    T[n * 256 + k] = f2bf(val);
}

// =====================================================================
// BK=64 m97-style bf16 MFMA GEMM: two 32-K sub-tiles (each the proven
// m97 layout: 128 rows x 32 k, 64B rows -> 2-way bank alias only)
// staged together via 8+8 global_load_lds(16B), then ONE barrier pair
// covering 32 MFMA/wave (2x the K-amortization of BK=32).
// 128x128 tile, 4 waves 2x2, wave = 64x64 via 4x4 mfma_f32_16x16x32.
// LDS 32 KB.  M-tail: load rows clamped, stores guarded.
// Staging map (per matrix, per sub-tile s): flat chunk f = u*256+tid
// (u=0,1), row=f>>2, kc=(f&3)*8; LDS ushort off = f*8 = wave-uniform
// (u*2048+wave*512) + lane*8  -> satisfies m104's lane*16B constraint.
// =====================================================================
template<bool C_BF16>
__device__ __forceinline__ void gemm_core(
    const ushort_t* __restrict__ A, const ushort_t* __restrict__ BT,
    const float* __restrict__ bias, void* __restrict__ Cv,
    int M, int Nc, int bm0, int bn0,
    ushort_t* __restrict__ As, ushort_t* __restrict__ Bs)
{
    const int tid  = threadIdx.x;
    const int wave = tid >> 6;
    const int lane = tid & 63;
    const int quad = lane >> 4;
    const int l16  = lane & 15;
    const int wm   = (wave >> 1) * 64;
    const int wn   = (wave & 1) * 64;

    // per-thread global sources for the two flat chunks (u=0,1)
    const int f0 = tid, f1 = tid + 256;
    const int r0 = f0 >> 2, k0 = (f0 & 3) * 8;
    const int r1 = f1 >> 2, k1 = (f1 & 3) * 8;
    int ar0 = bm0 + r0; if (ar0 > M - 1) ar0 = M - 1;
    int ar1 = bm0 + r1; if (ar1 > M - 1) ar1 = M - 1;
    const ushort_t* gA0 = A + (size_t)ar0 * 256 + k0;
    const ushort_t* gA1 = A + (size_t)ar1 * 256 + k1;
    const ushort_t* gB0 = BT + (size_t)(bn0 + r0) * 256 + k0;
    const ushort_t* gB1 = BT + (size_t)(bn0 + r1) * 256 + k1;

    // wave-uniform LDS bases (ushort units) for instr (s,u)
    ushort_t* lA[2][2], *lB[2][2];
    #pragma unroll
    for (int s = 0; s < 2; ++s)
        #pragma unroll
        for (int u = 0; u < 2; ++u) {
            lA[s][u] = As + s * 4096 + u * 2048 + wave * 512;
            lB[s][u] = Bs + s * 4096 + u * 2048 + wave * 512;
        }

    floatx4 acc[4][4];
    #pragma unroll
    for (int i = 0; i < 4; ++i)
        #pragma unroll
        for (int j = 0; j < 4; ++j)
            acc[i][j] = (floatx4){0.f, 0.f, 0.f, 0.f};

    for (int kk = 0; kk < 256; kk += 64) {
        // ---- stage both 32-K sub-tiles: 8 DMA instrs per matrix ----
        #pragma unroll
        for (int s = 0; s < 2; ++s) {
            const int ks = kk + s * 32;
            __builtin_amdgcn_global_load_lds(
                (const __attribute__((address_space(1))) void*)(gA0 + ks),
                (__attribute__((address_space(3))) void*)lA[s][0], 16, 0, 0);
            __builtin_amdgcn_global_load_lds(
                (const __attribute__((address_space(1))) void*)(gA1 + ks),
                (__attribute__((address_space(3))) void*)lA[s][1], 16, 0, 0);
            __builtin_amdgcn_global_load_lds(
                (const __attribute__((address_space(1))) void*)(gB0 + ks),
                (__attribute__((address_space(3))) void*)lB[s][0], 16, 0, 0);
            __builtin_amdgcn_global_load_lds(
                (const __attribute__((address_space(1))) void*)(gB1 + ks),
                (__attribute__((address_space(3))) void*)lB[s][1], 16, 0, 0);
        }
        __syncthreads();

        // ---- 32 MFMA per wave between barriers ----
        #pragma unroll
        for (int s = 0; s < 2; ++s) {
            const ushort_t* as = As + s * 4096;
            const ushort_t* bs = Bs + s * 4096;
            short8 af[4], bfr[4];
            #pragma unroll
            for (int mt = 0; mt < 4; ++mt)
                af[mt] = *(const short8*)&as[(wm + mt * 16 + l16) * 32 + quad * 8];
            #pragma unroll
            for (int nt = 0; nt < 4; ++nt)
                bfr[nt] = *(const short8*)&bs[(wn + nt * 16 + l16) * 32 + quad * 8];
            #pragma unroll
            for (int mt = 0; mt < 4; ++mt)
                #pragma unroll
                for (int nt = 0; nt < 4; ++nt)
                    acc[mt][nt] = __builtin_amdgcn_mfma_f32_16x16x32_bf16(
                        af[mt], bfr[nt], acc[mt][nt], 0, 0, 0);
        }
        __syncthreads();
    }

    // epilogue: D row = wm+mt*16+quad*4+j, col = wn+nt*16+l16 (m89 mapping)
    #pragma unroll
    for (int mt = 0; mt < 4; ++mt) {
        #pragma unroll
        for (int j = 0; j < 4; ++j) {
            const int row = bm0 + wm + mt * 16 + quad * 4 + j;
            if (row >= M) continue;
            #pragma unroll
            for (int nt = 0; nt < 4; ++nt) {
                const int col = bn0 + wn + nt * 16 + l16;
                const float val = acc[mt][nt][j] + bias[col];
                if (C_BF16) ((ushort_t*)Cv)[(size_t)row * Nc + col] = f2bf(val);
                else        ((float*)Cv)[(size_t)row * Nc + col]    = val;
            }
        }
    }
}

// Fused projection GEMMs: y<2 -> vproj = vbf@W_in (bf16 out, Nc=256);
// y in 2..4 -> offlog = qbf@[W_off|W_attn] (fp32 out, Nc=384).
__global__ __launch_bounds__(256) void gemm_proj_kernel(
    const ushort_t* __restrict__ vbf, const ushort_t* __restrict__ qbf,
    const ushort_t* __restrict__ Tin, const ushort_t* __restrict__ Tcomb,
    const float* __restrict__ b_in, const float* __restrict__ bcomb,
    ushort_t* __restrict__ vproj, float* __restrict__ offlog)
{
    __shared__ ushort_t As[8192];
    __shared__ ushort_t Bs[8192];
    const int bm0 = blockIdx.x * 128;
    const int y = blockIdx.y;
    if (y < 2)
        gemm_core<true>(vbf, Tin, b_in, vproj, M_TOT, 256, bm0, y * 128, As, Bs);
    else
        gemm_core<false>(qbf, Tcomb, bcomb, offlog, M_TOT, 384, bm0, (y - 2) * 128, As, Bs);
}

__global__ __launch_bounds__(256) void gemm_out_kernel(
    const ushort_t* __restrict__ mid, const ushort_t* __restrict__ Tout,
    const float* __restrict__ b_out, float* __restrict__ out)
{
    __shared__ ushort_t As[8192];
    __shared__ ushort_t Bs[8192];
    gemm_core<false>(mid, Tout, b_out, out, M_TOT, 256,
                     blockIdx.x * 128, blockIdx.y * 128, As, Bs);
}

// =====================================================================
// Sampling kernel v5 (measured 70-73 us at nominal clocks): 2 queries
// per 128-thread block, 8B bf16 gathers, slot stride 36 floats.
// =====================================================================
#define QB 2
#define SLOTS 576

__global__ __launch_bounds__(128) void msda_sample_kernel(
    const ushort_t* __restrict__ vproj, const float* __restrict__ offlog,
    const float* __restrict__ p, ushort_t* __restrict__ mid)
{
    __shared__ float s_logit[QB][128];
    __shared__ float s_off[QB][256];
    __shared__ float s_p[QB][8];
    __shared__ float s_mx[QB][HEADS];
    __shared__ float s_inv[QB][HEADS];
    __shared__ float s_w[QB][SLOTS];
    __shared__ int   s_idx[QB][SLOTS];

    const int tid = threadIdx.x;          // 0..127
    const int bq0 = blockIdx.x * QB;

    #pragma unroll
    for (int i = tid; i < QB * 256; i += 128) {
        int sub = i >> 8, j = i & 255;
        s_off[sub][j] = offlog[(size_t)(bq0 + sub) * 384 + j];
    }
    #pragma unroll
    for (int i = tid; i < QB * 128; i += 128) {
        int sub = i >> 7, j = i & 127;
        s_logit[sub][j] = offlog[(size_t)(bq0 + sub) * 384 + 256 + j];
    }
    if (tid < QB * 8) {
        int sub = tid >> 3, j = tid & 7;
        s_p[sub][j] = p[(size_t)(bq0 + sub) * 8 + j];
    }
    __syncthreads();

    if (tid < QB * HEADS) {
        int sub = tid >> 3, h = tid & 7;
        float mx = -1e30f;
        #pragma unroll
        for (int i = 0; i < 16; ++i) mx = fmaxf(mx, s_logit[sub][h * 16 + i]);
        float ssum = 0.0f;
        #pragma unroll
        for (int i = 0; i < 16; ++i) ssum += __expf(s_logit[sub][h * 16 + i] - mx);
        s_mx[sub][h] = mx;
        s_inv[sub][h] = 1.0f / ssum;
    }
    __syncthreads();

    // ---- phase 1: 256 tasks (sub, h, l, pt) over 128 threads ----
    #pragma unroll
    for (int tt = tid; tt < QB * 128; tt += 128) {
        const int sub = tt >> 7;
        const int j   = tt & 127;          // h*16 + l*4 + pt
        const int h   = j >> 4;
        const int l   = (j >> 2) & 3;
        const int nq  = bq0 + sub;
        const int nb  = (nq >= QN) ? 1 : 0;

        const int Hl = c_Hl[l], Wl = c_Wl[l], st = c_start[l];
        const float fW = (float)Wl, fH = (float)Hl;

        const float w = __expf(s_logit[sub][j] - s_mx[sub][h]) * s_inv[sub][h];

        const int oi = j * 2;
        const float ox = s_off[sub][oi];
        const float oy = s_off[sub][oi + 1];
        const float px = s_p[sub][l * 2 + 0];
        const float py = s_p[sub][l * 2 + 1];

        const float lx = px + ox / fW;
        const float ly = py + oy / fH;
        const float x = lx * fW - 0.5f;
        const float y = ly * fH - 0.5f;

        const float x0f = floorf(x), y0f = floorf(y);
        const int x0 = (int)x0f, y0 = (int)y0f;
        const float dx = x - x0f, dy = y - y0f;

        const int base = nb * (HW_TOT * DIMS) + h * CH;
        const int slot = (j & 15) * 36 + h * 4;

        const bool vx0 = (x0 >= 0) & (x0 < Wl);
        const bool vx1 = (x0 + 1 >= 0) & (x0 + 1 < Wl);
        const bool vy0 = (y0 >= 0) & (y0 < Hl);
        const bool vy1 = (y0 + 1 >= 0) & (y0 + 1 < Hl);

        s_w[sub][slot + 0] = (vx0 & vy0) ? w * (1.0f - dx) * (1.0f - dy) : 0.0f;
        s_w[sub][slot + 1] = (vx1 & vy0) ? w * dx * (1.0f - dy) : 0.0f;
        s_w[sub][slot + 2] = (vx0 & vy1) ? w * (1.0f - dx) * dy : 0.0f;
        s_w[sub][slot + 3] = (vx1 & vy1) ? w * dx * dy : 0.0f;
        s_idx[sub][slot + 0] = (vx0 & vy0) ? base + (st + y0 * Wl + x0) * DIMS : 0;
        s_idx[sub][slot + 1] = (vx1 & vy0) ? base + (st + y0 * Wl + x0 + 1) * DIMS : 0;
        s_idx[sub][slot + 2] = (vx0 & vy1) ? base + (st + (y0 + 1) * Wl + x0) * DIMS : 0;
        s_idx[sub][slot + 3] = (vx1 & vy1) ? base + (st + (y0 + 1) * Wl + x0 + 1) * DIMS : 0;
    }
    __syncthreads();

    // ---- phase 2: bf16 gathers (uint2 = 4 channels), fp32 accumulate ----
    const int sub  = tid >> 6;
    const int lane = tid & 63;
    const int h    = lane >> 3;
    const int c4   = lane & 7;
    const int nq   = bq0 + sub;

    float ax = 0.0f, ay = 0.0f, az = 0.0f, aw = 0.0f;
    const ushort_t* __restrict__ vb = vproj + c4 * 4;

    #pragma unroll
    for (int t = 0; t < 16; ++t) {
        const int slot = t * 36 + h * 4;
        const int4   I = *(const int4*)&s_idx[sub][slot];
        const float4 W = *(const float4*)&s_w[sub][slot];

        const uint2 g0 = *(const uint2*)(vb + I.x);
        const uint2 g1 = *(const uint2*)(vb + I.y);
        const uint2 g2 = *(const uint2*)(vb + I.z);
        const uint2 g3 = *(const uint2*)(vb + I.w);

        ax = fmaf(W.x, __uint_as_float(g0.x << 16), ax);
        ay = fmaf(W.x, __uint_as_float(g0.x & 0xffff0000u), ay);
        az = fmaf(W.x, __uint_as_float(g0.y << 16), az);
        aw = fmaf(W.x, __uint_as_float(g0.y & 0xffff0000u), aw);

        ax = fmaf(W.y, __uint_as_float(g1.x << 16), ax);
        ay = fmaf(W.y, __uint_as_float(g1.x & 0xffff0000u), ay);
        az = fmaf(W.y, __uint_as_float(g1.y << 16), az);
        aw = fmaf(W.y, __uint_as_float(g1.y & 0xffff0000u), aw);

        ax = fmaf(W.z, __uint_as_float(g2.x << 16), ax);
        ay = fmaf(W.z, __uint_as_float(g2.x & 0xffff0000u), ay);
        az = fmaf(W.z, __uint_as_float(g2.y << 16), az);
        aw = fmaf(W.z, __uint_as_float(g2.y & 0xffff0000u), aw);

        ax = fmaf(W.w, __uint_as_float(g3.x << 16), ax);
        ay = fmaf(W.w, __uint_as_float(g3.x & 0xffff0000u), ay);
        az = fmaf(W.w, __uint_as_float(g3.y << 16), az);
        aw = fmaf(W.w, __uint_as_float(g3.y & 0xffff0000u), aw);
    }

    ushort_t mv[4] = {f2bf(ax), f2bf(ay), f2bf(az), f2bf(aw)};
    *(uint2*)&mid[(size_t)nq * DIMS + lane * 4] = *(uint2*)mv;
}

// =====================================================================
extern "C" void kernel_launch(void* const* d_in, const int* in_sizes, int n_in,
                              void* d_out, int out_size, void* d_ws, size_t ws_size,
                              hipStream_t stream)
{
    const float* q      = (const float*)d_in[0];
    const float* p      = (const float*)d_in[1];
    const float* v      = (const float*)d_in[2];
    const float* W_off  = (const float*)d_in[3];
    const float* b_off  = (const float*)d_in[4];
    const float* W_attn = (const float*)d_in[5];
    const float* b_attn = (const float*)d_in[6];
    const float* W_in   = (const float*)d_in[7];
    const float* b_in   = (const float*)d_in[8];
    const float* W_out  = (const float*)d_in[9];
    const float* b_out  = (const float*)d_in[10];
    float* out = (float*)d_out;

    const int M = M_TOT;                            // 24480

    // workspace layout (mid aliases vbf -- vbf dead after proj GEMM)
    ushort_t* vproj  = (ushort_t*)d_ws;                          // M*256 bf16
    float*    offlog = (float*)(vproj + (size_t)M * 256);        // M*384 f32
    ushort_t* vbf    = (ushort_t*)(offlog + (size_t)M * 384);    // M*256 bf16
    ushort_t* mid    = vbf;                                      // alias
    ushort_t* qbf    = vbf + (size_t)M * 256;                    // M*256 bf16
    ushort_t* Tin    = qbf + (size_t)M * 256;
    ushort_t* Tcomb  = Tin + 256 * 256;
    ushort_t* Tout   = Tcomb + 384 * 256;
    float*    bcomb  = (float*)(Tout + 256 * 256);

    // 0a) v,q -> bf16
    convert_qv_kernel<<<dim3(6120), 256, 0, stream>>>(v, q, vbf, qbf);
    // 0b) weights -> transposed bf16 (+ fused off/attn weight & bias)
    prep_weights_kernel<<<dim3(384, 1, 3), 256, 0, stream>>>(
        W_in, W_off, W_attn, W_out, b_off, b_attn, Tin, Tcomb, Tout, bcomb);

    // 1+2+3) fused projection GEMMs (BK=64, 32 MFMA per barrier-pair)
    gemm_proj_kernel<<<dim3(192, 5), 256, 0, stream>>>(
        vbf, qbf, Tin, Tcomb, b_in, bcomb, vproj, offlog);
    // 4) softmax + bilinear sampling -> bf16 mid
    msda_sample_kernel<<<dim3(M / QB), 128, 0, stream>>>(vproj, offlog, p, mid);
    // 5) out = mid @ W_out + b_out
    gemm_out_kernel<<<dim3(192, 2), 256, 0, stream>>>(mid, Tout, b_out, out);
}